// Round 1
// baseline (146.996 us; speedup 1.0000x reference)
//
#include <hip/hip_runtime.h>
#include <math.h>

#define NPTS 8192

struct Xforms { float B[3][4]; float R[3][4]; float T[3][4]; };

__device__ __forceinline__ void compute_xforms(const float* __restrict__ quat,
                                               const float* __restrict__ bt,
                                               const float* __restrict__ anchor,
                                               const float* __restrict__ axis,
                                               const float* __restrict__ theta,
                                               Xforms& X) {
  // base transform from quaternion + translation
  float q0 = quat[0], q1 = quat[1], q2 = quat[2], q3 = quat[3];
  float n = sqrtf(q0 * q0 + q1 * q1 + q2 * q2 + q3 * q3);
  float a = q0 / n, b = q1 / n, c = q2 / n, d = q3 / n;
  X.B[0][0] = 1.f - 2.f * c * c - 2.f * d * d;
  X.B[0][1] = 2.f * b * c - 2.f * a * d;
  X.B[0][2] = 2.f * a * c + 2.f * b * d;
  X.B[0][3] = bt[0];
  X.B[1][0] = 2.f * b * c + 2.f * a * d;
  X.B[1][1] = 1.f - 2.f * b * b - 2.f * d * d;
  X.B[1][2] = 2.f * c * d - 2.f * a * b;
  X.B[1][3] = bt[1];
  X.B[2][0] = 2.f * b * d - 2.f * a * c;
  X.B[2][1] = 2.f * a * b + 2.f * c * d;
  X.B[2][2] = 1.f - 2.f * b * b - 2.f * c * c;
  X.B[2][3] = bt[2];

  // revolute (screw) transform; axis is NOT normalized in the reference
  float ax = anchor[0], ay = anchor[1], az = anchor[2];
  float u = axis[0], v = axis[1], w = axis[2];
  float th = theta[0];
  float cs = cosf(th), sn = sinf(th), oc = 1.f - cs;
  X.R[0][0] = u * u + (v * v + w * w) * cs;
  X.R[0][1] = u * v * oc - w * sn;
  X.R[0][2] = u * w * oc + v * sn;
  X.R[0][3] = (ax * (v * v + w * w) - u * (ay * v + az * w)) * oc + (ay * w - az * v) * sn;
  X.R[1][0] = u * v * oc + w * sn;
  X.R[1][1] = v * v + (u * u + w * w) * cs;
  X.R[1][2] = v * w * oc - u * sn;
  X.R[1][3] = (ay * (u * u + w * w) - v * (ax * u + az * w)) * oc + (az * u - ax * w) * sn;
  X.R[2][0] = u * w * oc - v * sn;
  X.R[2][1] = v * w * oc + u * sn;
  X.R[2][2] = w * w + (u * u + v * v) * cs;
  X.R[2][3] = (az * (u * u + v * v) - w * (ax * u + ay * v)) * oc + (ax * v - ay * u) * sn;

  // T = [R;0 0 0 1] @ [B;0 0 0 1], top 3 rows
#pragma unroll
  for (int i = 0; i < 3; i++) {
#pragma unroll
    for (int j = 0; j < 4; j++) {
      float s = X.R[i][0] * X.B[0][j] + X.R[i][1] * X.B[1][j] + X.R[i][2] * X.B[2][j];
      if (j == 3) s += X.R[i][3];
      X.T[i][j] = s;
    }
  }
}

__global__ void init_kernel(unsigned int* __restrict__ minarr) {
  int i = blockIdx.x * blockDim.x + threadIdx.x;
  if (i < 4 * NPTS) minarr[i] = 0x7f800000u;  // +inf
}

// grid: (src_chunks=8, tgt_chunks=8, combos=4), block 256
// combo = part*2 + dir.  dir 0: src = transformed cad, tgt = cam
//                        dir 1: src = cam, tgt = transformed cad
__global__ __launch_bounds__(256) void chamfer_kernel(
    const float* __restrict__ cam, const float* __restrict__ cad,
    const float* __restrict__ quat, const float* __restrict__ bt,
    const float* __restrict__ anchor, const float* __restrict__ axis,
    const float* __restrict__ theta,
    unsigned int* __restrict__ minarr) {
  Xforms X;
  compute_xforms(quat, bt, anchor, axis, theta, X);

  const int combo = blockIdx.z;
  const int part = combo >> 1;
  const int dir = combo & 1;

  // per-element select keeps M in registers (no pointer-to-stack scratch)
  float M[3][4];
#pragma unroll
  for (int i = 0; i < 3; i++)
#pragma unroll
    for (int j = 0; j < 4; j++) M[i][j] = part ? X.T[i][j] : X.B[i][j];

  const float* cadp = cad + part * NPTS * 3;
  const float* camp = cam + part * NPTS * 3;
  const float* srcp = dir ? camp : cadp;
  const float* tgtp = dir ? cadp : camp;
  const bool src_xf = (dir == 0);
  const bool tgt_xf = (dir == 1);

  const int tid = threadIdx.x;
  const int sbase = blockIdx.x * 1024;

  float sx[4], sy[4], sz[4], dmin[4];
#pragma unroll
  for (int i = 0; i < 4; i++) {
    int idx = sbase + i * 256 + tid;
    float px = srcp[idx * 3 + 0], py = srcp[idx * 3 + 1], pz = srcp[idx * 3 + 2];
    if (src_xf) {
      float qx = M[0][0] * px + M[0][1] * py + M[0][2] * pz + M[0][3];
      float qy = M[1][0] * px + M[1][1] * py + M[1][2] * pz + M[1][3];
      float qz = M[2][0] * px + M[2][1] * py + M[2][2] * pz + M[2][3];
      px = qx; py = qy; pz = qz;
    }
    sx[i] = px; sy[i] = py; sz[i] = pz;
    dmin[i] = 3.4e38f;
  }

  __shared__ float tlx[256], tly[256], tlz[256];
  const int tbase = blockIdx.y * 1024;

  for (int tt = 0; tt < 1024; tt += 256) {
    int idx = tbase + tt + tid;
    float px = tgtp[idx * 3 + 0], py = tgtp[idx * 3 + 1], pz = tgtp[idx * 3 + 2];
    if (tgt_xf) {
      float qx = M[0][0] * px + M[0][1] * py + M[0][2] * pz + M[0][3];
      float qy = M[1][0] * px + M[1][1] * py + M[1][2] * pz + M[1][3];
      float qz = M[2][0] * px + M[2][1] * py + M[2][2] * pz + M[2][3];
      px = qx; py = qy; pz = qz;
    }
    __syncthreads();
    tlx[tid] = px; tly[tid] = py; tlz[tid] = pz;
    __syncthreads();

#pragma unroll 4
    for (int k = 0; k < 256; k++) {
      float tx = tlx[k], ty = tly[k], tz = tlz[k];  // same-addr -> LDS broadcast
#pragma unroll
      for (int i = 0; i < 4; i++) {
        float dx = sx[i] - tx, dy = sy[i] - ty, dz = sz[i] - tz;
        float d2 = fmaf(dx, dx, fmaf(dy, dy, dz * dz));
        dmin[i] = fminf(dmin[i], d2);
      }
    }
  }

  // d2 >= 0 so uint bit-pattern ordering == float ordering
#pragma unroll
  for (int i = 0; i < 4; i++) {
    atomicMin(minarr + combo * NPTS + sbase + i * 256 + tid, __float_as_uint(dmin[i]));
  }
}

__global__ __launch_bounds__(256) void reduce_kernel(const unsigned int* __restrict__ minarr,
                                                     float* __restrict__ sums) {
  const int combo = blockIdx.x;
  float s = 0.f;
  for (int i = threadIdx.x; i < NPTS; i += 256)
    s += sqrtf(__uint_as_float(minarr[combo * NPTS + i]));
#pragma unroll
  for (int off = 32; off > 0; off >>= 1) s += __shfl_down(s, off);
  __shared__ float part[4];
  if ((threadIdx.x & 63) == 0) part[threadIdx.x >> 6] = s;
  __syncthreads();
  if (threadIdx.x == 0) sums[combo] = part[0] + part[1] + part[2] + part[3];
}

__global__ void finalize_kernel(const float* __restrict__ sums,
                                const float* __restrict__ pw,
                                const float* __restrict__ quat,
                                const float* __restrict__ bt,
                                const float* __restrict__ anchor,
                                const float* __restrict__ axis,
                                const float* __restrict__ theta,
                                float* __restrict__ out) {
  if (threadIdx.x != 0 || blockIdx.x != 0) return;
  Xforms X;
  compute_xforms(quat, bt, anchor, axis, theta, X);
  const float inv = 1.0f / (float)NPTS;
  float base_obj = (sums[0] + sums[1]) * inv;
  float child_obj = (sums[2] + sums[3]) * inv;
  float all = (pw[0] * base_obj + pw[1] * child_obj) * 0.5f;
  out[0] = all;
  out[1] = base_obj;
  out[2] = child_obj;
  // base_transform 4x4 row-major at out[3..18]
  for (int i = 0; i < 3; i++)
    for (int j = 0; j < 4; j++) out[3 + i * 4 + j] = X.B[i][j];
  out[15] = 0.f; out[16] = 0.f; out[17] = 0.f; out[18] = 1.f;
  // relative_transform 4x4 at out[19..34]
  for (int i = 0; i < 3; i++)
    for (int j = 0; j < 4; j++) out[19 + i * 4 + j] = X.R[i][j];
  out[31] = 0.f; out[32] = 0.f; out[33] = 0.f; out[34] = 1.f;
}

extern "C" void kernel_launch(void* const* d_in, const int* in_sizes, int n_in,
                              void* d_out, int out_size, void* d_ws, size_t ws_size,
                              hipStream_t stream) {
  const float* cam  = (const float*)d_in[0];  // [2,8192,3]
  const float* cad  = (const float*)d_in[1];  // [2,8192,3]
  const float* xyz  = (const float*)d_in[2];  // [1,3] anchor
  const float* rpy  = (const float*)d_in[3];  // [1,3] axis
  const float* pw   = (const float*)d_in[4];  // [2]
  const float* quat = (const float*)d_in[5];  // [4]
  const float* bt   = (const float*)d_in[6];  // [3,1]
  const float* js   = (const float*)d_in[7];  // [1]

  unsigned int* minarr = (unsigned int*)d_ws;                       // 4*8192 u32
  float* sums = (float*)((char*)d_ws + 4 * NPTS * sizeof(unsigned)); // 4 floats
  float* out = (float*)d_out;

  hipLaunchKernelGGL(init_kernel, dim3(128), dim3(256), 0, stream, minarr);
  hipLaunchKernelGGL(chamfer_kernel, dim3(8, 8, 4), dim3(256), 0, stream,
                     cam, cad, quat, bt, xyz, rpy, js, minarr);
  hipLaunchKernelGGL(reduce_kernel, dim3(4), dim3(256), 0, stream, minarr, sums);
  hipLaunchKernelGGL(finalize_kernel, dim3(1), dim3(64), 0, stream,
                     sums, pw, quat, bt, xyz, rpy, js, out);
}

// Round 2
// 100.689 us; speedup vs baseline: 1.4599x; 1.4599x over previous
//
#include <hip/hip_runtime.h>
#include <math.h>

#define NPTS 8192

struct Xforms { float B[3][4]; float R[3][4]; float T[3][4]; };

__device__ __forceinline__ void compute_xforms(const float* __restrict__ quat,
                                               const float* __restrict__ bt,
                                               const float* __restrict__ anchor,
                                               const float* __restrict__ axis,
                                               const float* __restrict__ theta,
                                               Xforms& X) {
  float q0 = quat[0], q1 = quat[1], q2 = quat[2], q3 = quat[3];
  float n = sqrtf(q0 * q0 + q1 * q1 + q2 * q2 + q3 * q3);
  float a = q0 / n, b = q1 / n, c = q2 / n, d = q3 / n;
  X.B[0][0] = 1.f - 2.f * c * c - 2.f * d * d;
  X.B[0][1] = 2.f * b * c - 2.f * a * d;
  X.B[0][2] = 2.f * a * c + 2.f * b * d;
  X.B[0][3] = bt[0];
  X.B[1][0] = 2.f * b * c + 2.f * a * d;
  X.B[1][1] = 1.f - 2.f * b * b - 2.f * d * d;
  X.B[1][2] = 2.f * c * d - 2.f * a * b;
  X.B[1][3] = bt[1];
  X.B[2][0] = 2.f * b * d - 2.f * a * c;
  X.B[2][1] = 2.f * a * b + 2.f * c * d;
  X.B[2][2] = 1.f - 2.f * b * b - 2.f * c * c;
  X.B[2][3] = bt[2];

  float ax = anchor[0], ay = anchor[1], az = anchor[2];
  float u = axis[0], v = axis[1], w = axis[2];
  float th = theta[0];
  float cs = cosf(th), sn = sinf(th), oc = 1.f - cs;
  X.R[0][0] = u * u + (v * v + w * w) * cs;
  X.R[0][1] = u * v * oc - w * sn;
  X.R[0][2] = u * w * oc + v * sn;
  X.R[0][3] = (ax * (v * v + w * w) - u * (ay * v + az * w)) * oc + (ay * w - az * v) * sn;
  X.R[1][0] = u * v * oc + w * sn;
  X.R[1][1] = v * v + (u * u + w * w) * cs;
  X.R[1][2] = v * w * oc - u * sn;
  X.R[1][3] = (ay * (u * u + w * w) - v * (ax * u + az * w)) * oc + (az * u - ax * w) * sn;
  X.R[2][0] = u * w * oc - v * sn;
  X.R[2][1] = v * w * oc + u * sn;
  X.R[2][2] = w * w + (u * u + v * v) * cs;
  X.R[2][3] = (az * (u * u + v * v) - w * (ax * u + ay * v)) * oc + (ax * v - ay * u) * sn;

#pragma unroll
  for (int i = 0; i < 3; i++) {
#pragma unroll
    for (int j = 0; j < 4; j++) {
      float s = X.R[i][0] * X.B[0][j] + X.R[i][1] * X.B[1][j] + X.R[i][2] * X.B[2][j];
      if (j == 3) s += X.R[i][3];
      X.T[i][j] = s;
    }
  }
}

// prep: init minarr to +inf, zero sums/counter, and write all 4 point sets as
// float4(x,y,z,0.5*|p|^2):  a=0: B*cad0, a=1: cam0, a=2: T*cad1, a=3: cam1
__global__ __launch_bounds__(256) void prep_kernel(
    const float* __restrict__ cam, const float* __restrict__ cad,
    const float* __restrict__ quat, const float* __restrict__ bt,
    const float* __restrict__ anchor, const float* __restrict__ axis,
    const float* __restrict__ theta,
    float4* __restrict__ pts4, unsigned int* __restrict__ minarr,
    float* __restrict__ sums, unsigned int* __restrict__ counter) {
  int gid = blockIdx.x * 256 + threadIdx.x;  // 0..32767
  minarr[gid] = 0x7f800000u;                 // +inf bit pattern
  if (gid < 4) sums[gid] = 0.f;
  if (gid == 0) *counter = 0u;

  Xforms X;
  compute_xforms(quat, bt, anchor, axis, theta, X);

  int a = gid >> 13;      // which array
  int i = gid & 8191;     // point index
  int part = a >> 1;
  const float* base = ((a & 1) ? cam : cad) + part * NPTS * 3;
  float px = base[i * 3 + 0], py = base[i * 3 + 1], pz = base[i * 3 + 2];
  if ((a & 1) == 0) {
    // per-element select keeps M in registers
    float M[3][4];
#pragma unroll
    for (int r = 0; r < 3; r++)
#pragma unroll
      for (int cc = 0; cc < 4; cc++) M[r][cc] = part ? X.T[r][cc] : X.B[r][cc];
    float qx = M[0][0] * px + M[0][1] * py + M[0][2] * pz + M[0][3];
    float qy = M[1][0] * px + M[1][1] * py + M[1][2] * pz + M[1][3];
    float qz = M[2][0] * px + M[2][1] * py + M[2][2] * pz + M[2][3];
    px = qx; py = qy; pz = qz;
  }
  float h = 0.5f * (px * px + py * py + pz * pz);
  pts4[gid] = make_float4(px, py, pz, h);
}

// grid (4 src-chunks, 32 tgt-chunks, 4 combos), block 256.
// combo c: src array = c, tgt array = c^1.  8 src pts/thread, 256-pt tgt tile.
// min d^2 = 2*(s.w + min_k(t.w - s·t)) — 3 FMA + 1 min per pair.
__global__ __launch_bounds__(256) void chamfer_kernel(
    const float4* __restrict__ pts4, unsigned int* __restrict__ minarr) {
  const int combo = blockIdx.z;
  const int tid = threadIdx.x;
  const float4* __restrict__ srcp = pts4 + combo * NPTS;
  const float4* __restrict__ tgtp = pts4 + (combo ^ 1) * NPTS;

  const int sbase = blockIdx.x * 2048;

  float4 s[8];
  float vmin[8];
#pragma unroll
  for (int i = 0; i < 8; i++) {
    s[i] = srcp[sbase + i * 256 + tid];
    vmin[i] = 3.4e38f;
  }

  __shared__ float4 tile[256];
  tile[tid] = tgtp[blockIdx.y * 256 + tid];
  __syncthreads();

#pragma unroll 4
  for (int k = 0; k < 256; k++) {
    float4 t = tile[k];  // same-address LDS read -> broadcast, conflict-free
#pragma unroll
    for (int i = 0; i < 8; i++) {
      float v = fmaf(-s[i].z, t.z, t.w);
      v = fmaf(-s[i].y, t.y, v);
      v = fmaf(-s[i].x, t.x, v);
      vmin[i] = fminf(vmin[i], v);
    }
  }

#pragma unroll
  for (int i = 0; i < 8; i++) {
    float d2 = fmaxf(0.f, 2.f * (s[i].w + vmin[i]));  // clamp: keep sign bit clear
    atomicMin(minarr + combo * NPTS + sbase + i * 256 + tid, __float_as_uint(d2));
  }
}

// 32 blocks: 8 per combo, 1024 pts each. atomicAdd partial sqrt-sums, then
// last-block-done pattern finalizes outputs (device-scope atomics, XCD-safe).
__global__ __launch_bounds__(256) void reduce_finalize_kernel(
    const unsigned int* __restrict__ minarr, float* __restrict__ sums,
    unsigned int* __restrict__ counter,
    const float* __restrict__ pw,
    const float* __restrict__ quat, const float* __restrict__ bt,
    const float* __restrict__ anchor, const float* __restrict__ axis,
    const float* __restrict__ theta, float* __restrict__ out) {
  const int tid = threadIdx.x;
  const int combo = blockIdx.x >> 3;
  const int chunk = blockIdx.x & 7;
  const int base = combo * NPTS + chunk * 1024;

  float ssum = 0.f;
#pragma unroll
  for (int j = 0; j < 4; j++)
    ssum += sqrtf(__uint_as_float(minarr[base + j * 256 + tid]));

#pragma unroll
  for (int off = 32; off > 0; off >>= 1) ssum += __shfl_down(ssum, off);
  __shared__ float part[4];
  if ((tid & 63) == 0) part[tid >> 6] = ssum;
  __syncthreads();

  if (tid == 0) {
    float blocksum = part[0] + part[1] + part[2] + part[3];
    atomicAdd(&sums[combo], blocksum);
    __threadfence();
    unsigned int old = atomicAdd(counter, 1u);
    if (old == 31u) {  // all other blocks' sums are visible
      __threadfence();
      float s0 = __hip_atomic_load(&sums[0], __ATOMIC_ACQUIRE, __HIP_MEMORY_SCOPE_AGENT);
      float s1 = __hip_atomic_load(&sums[1], __ATOMIC_ACQUIRE, __HIP_MEMORY_SCOPE_AGENT);
      float s2 = __hip_atomic_load(&sums[2], __ATOMIC_ACQUIRE, __HIP_MEMORY_SCOPE_AGENT);
      float s3 = __hip_atomic_load(&sums[3], __ATOMIC_ACQUIRE, __HIP_MEMORY_SCOPE_AGENT);
      Xforms X;
      compute_xforms(quat, bt, anchor, axis, theta, X);
      const float inv = 1.0f / (float)NPTS;
      float base_obj = (s0 + s1) * inv;
      float child_obj = (s2 + s3) * inv;
      out[0] = (pw[0] * base_obj + pw[1] * child_obj) * 0.5f;
      out[1] = base_obj;
      out[2] = child_obj;
      for (int i = 0; i < 3; i++)
        for (int j = 0; j < 4; j++) out[3 + i * 4 + j] = X.B[i][j];
      out[15] = 0.f; out[16] = 0.f; out[17] = 0.f; out[18] = 1.f;
      for (int i = 0; i < 3; i++)
        for (int j = 0; j < 4; j++) out[19 + i * 4 + j] = X.R[i][j];
      out[31] = 0.f; out[32] = 0.f; out[33] = 0.f; out[34] = 1.f;
    }
  }
}

extern "C" void kernel_launch(void* const* d_in, const int* in_sizes, int n_in,
                              void* d_out, int out_size, void* d_ws, size_t ws_size,
                              hipStream_t stream) {
  const float* cam  = (const float*)d_in[0];  // [2,8192,3]
  const float* cad  = (const float*)d_in[1];  // [2,8192,3]
  const float* xyz  = (const float*)d_in[2];  // [1,3] anchor
  const float* rpy  = (const float*)d_in[3];  // [1,3] axis
  const float* pw   = (const float*)d_in[4];  // [2]
  const float* quat = (const float*)d_in[5];  // [4]
  const float* bt   = (const float*)d_in[6];  // [3,1]
  const float* js   = (const float*)d_in[7];  // [1]

  // ws layout: minarr 128 KB | pts4 512 KB | sums 16 B | counter 4 B
  unsigned int* minarr = (unsigned int*)d_ws;
  float4* pts4 = (float4*)((char*)d_ws + 4 * NPTS * sizeof(unsigned int));
  float* sums = (float*)((char*)d_ws + 4 * NPTS * sizeof(unsigned int) + 4 * NPTS * sizeof(float4));
  unsigned int* counter = (unsigned int*)(sums + 4);
  float* out = (float*)d_out;

  hipLaunchKernelGGL(prep_kernel, dim3(128), dim3(256), 0, stream,
                     cam, cad, quat, bt, xyz, rpy, js, pts4, minarr, sums, counter);
  hipLaunchKernelGGL(chamfer_kernel, dim3(4, 32, 4), dim3(256), 0, stream,
                     pts4, minarr);
  hipLaunchKernelGGL(reduce_finalize_kernel, dim3(32), dim3(256), 0, stream,
                     minarr, sums, counter, pw, quat, bt, xyz, rpy, js, out);
}